// Round 1
// 3482.462 us; speedup vs baseline: 1.3049x; 1.3049x over previous
//
#include <hip/hip_runtime.h>

// SimpleLSTM B=128,T=8192,H=96. R14: two batches packed into the MFMA
// B-operand COLUMNS (cols 0-7 = batch 2b, cols 8-15 = batch 2b+1). A 4-wave
// block (256 thr) now serves 2 batches with the same 18 MFMAs/wave that
// previously served one: lane's column picks its batch, sel=(col&7) mapped
// to 0..5 picks the tile, so each lane still owns exactly 1 cell. This
// halves per-SIMD MFMA+VALU issue (1 wave/SIMD, no issue contention),
// shrinks the barrier 8->4 waves, removes the cross-group lockstep coupling
// of R9/R13, and halves the post-barrier LDS burst. y-tile MFMA yields BOTH
// batches' y (cols 0 and 8, row 0). B-frag addresses (bsub*192B + quad*16B
// + kt*64B) hit all 32 banks conflict-free. Everything else (permuted W
// rows, exp2-domain prescale, named scalars, pinned A-frags, x prefetch,
// y ring flush) carried from R13.

#define T_LEN 8192
#define H_DIM 96
#define NTHR  256   // 4 waves, one batch-pair per block
#define CHUNK 128
#define LOG2E 1.44269504f

typedef float    f32x4 __attribute__((ext_vector_type(4)));
typedef _Float16 half8 __attribute__((ext_vector_type(8)));

#define MFMA16(A, B, C)                                                        \
    __builtin_amdgcn_mfma_f32_16x16x32_f16(__builtin_bit_cast(half8, (A)),     \
                                           __builtin_bit_cast(half8, (B)),     \
                                           (C), 0, 0, 0)

__device__ __forceinline__ float sig2(float s) {   // sigmoid, s = log2e*pre
    return __builtin_amdgcn_rcpf(1.0f + __builtin_amdgcn_exp2f(-s));
}
__device__ __forceinline__ float tanh2(float sg) { // tanh, sg = 2log2e*pre
    return 1.0f - 2.0f * __builtin_amdgcn_rcpf(1.0f + __builtin_amdgcn_exp2f(sg));
}

__device__ __forceinline__ f32x4 load_afrag(const float* __restrict__ w_hh,
                                            const float* __restrict__ w_out,
                                            int mt, int kt, int m, int quad) {
    half8 f;
    if (mt < 24) {
        const int r = m & 3;                       // gate: 0=i 1=f 2=g 3=o
        const float scale = (r == 2) ? 2.0f * LOG2E : LOG2E;
        const int orig = r * 96 + 4 * mt + (m >> 2);
        const float* src = w_hh + orig * H_DIM + kt * 32 + quad * 8;
        #pragma unroll
        for (int jj = 0; jj < 8; ++jj) f[jj] = (_Float16)(scale * src[jj]);
    } else {  // y tile: row 0 = w_out (unscaled), rows 1..15 = 0
        #pragma unroll
        for (int jj = 0; jj < 8; ++jj)
            f[jj] = (m == 0) ? (_Float16)w_out[kt * 32 + quad * 8 + jj]
                             : (_Float16)0.0f;
    }
    return __builtin_bit_cast(f32x4, f);
}

__global__ __launch_bounds__(NTHR, 2) void lstm_mfma14_kernel(
    const float* __restrict__ x,      // [B, T]
    const float* __restrict__ w_ih,   // [4H]
    const float* __restrict__ w_hh,   // [4H, H]
    const float* __restrict__ b_ih,   // [4H]
    const float* __restrict__ b_hh,   // [4H]
    const float* __restrict__ w_out,  // [H]
    const float* __restrict__ b_out,  // [1]
    float* __restrict__ y)            // [B, T]
{
    const int tid  = threadIdx.x;
    const int wv   = tid >> 6;        // wave 0..3
    const int lane = tid & 63;
    const int m    = lane & 15;       // A-row / D-column index
    const int quad = lane >> 4;       // D row group / B K-chunk
    const int cc   = m & 7;           // within-batch column
    const int bsub = m >> 3;          // 0: batch 2b, 1: batch 2b+1

    __shared__ __align__(16) _Float16 h_s[2][2][H_DIM];   // [buf][bsub][cell]
    __shared__ __align__(16) float    y_buf[2][2][CHUNK]; // [bsub][ring][i]
    __shared__ __align__(16) float    x_s[2][T_LEN];      // 64 KB

    // ---- stage both batches' x into LDS (rows 2b, 2b+1 are contiguous)
    {
        const float* xpair = x + (size_t)(2 * blockIdx.x) * T_LEN;
        float* xs = &x_s[0][0];
        for (int i = tid * 4; i < 2 * T_LEN; i += NTHR * 4)
            *reinterpret_cast<f32x4*>(&xs[i]) =
                *reinterpret_cast<const f32x4*>(&xpair[i]);
    }

    // ---- A fragments (named, pinned). wv owns tiles 6wv..6wv+5; wv3: +y tile
    const int mt0 = 6 * wv;
    f32x4 af00 = load_afrag(w_hh, w_out, mt0 + 0, 0, m, quad);
    f32x4 af01 = load_afrag(w_hh, w_out, mt0 + 0, 1, m, quad);
    f32x4 af02 = load_afrag(w_hh, w_out, mt0 + 0, 2, m, quad);
    f32x4 af10 = load_afrag(w_hh, w_out, mt0 + 1, 0, m, quad);
    f32x4 af11 = load_afrag(w_hh, w_out, mt0 + 1, 1, m, quad);
    f32x4 af12 = load_afrag(w_hh, w_out, mt0 + 1, 2, m, quad);
    f32x4 af20 = load_afrag(w_hh, w_out, mt0 + 2, 0, m, quad);
    f32x4 af21 = load_afrag(w_hh, w_out, mt0 + 2, 1, m, quad);
    f32x4 af22 = load_afrag(w_hh, w_out, mt0 + 2, 2, m, quad);
    f32x4 af30 = load_afrag(w_hh, w_out, mt0 + 3, 0, m, quad);
    f32x4 af31 = load_afrag(w_hh, w_out, mt0 + 3, 1, m, quad);
    f32x4 af32 = load_afrag(w_hh, w_out, mt0 + 3, 2, m, quad);
    f32x4 af40 = load_afrag(w_hh, w_out, mt0 + 4, 0, m, quad);
    f32x4 af41 = load_afrag(w_hh, w_out, mt0 + 4, 1, m, quad);
    f32x4 af42 = load_afrag(w_hh, w_out, mt0 + 4, 2, m, quad);
    f32x4 af50 = load_afrag(w_hh, w_out, mt0 + 5, 0, m, quad);
    f32x4 af51 = load_afrag(w_hh, w_out, mt0 + 5, 1, m, quad);
    f32x4 af52 = load_afrag(w_hh, w_out, mt0 + 5, 2, m, quad);
    f32x4 afy0 = {0.f, 0.f, 0.f, 0.f};
    f32x4 afy1 = {0.f, 0.f, 0.f, 0.f};
    f32x4 afy2 = {0.f, 0.f, 0.f, 0.f};
    if (wv == 3) {
        afy0 = load_afrag(w_hh, w_out, 24, 0, m, quad);
        afy1 = load_afrag(w_hh, w_out, 24, 1, m, quad);
        afy2 = load_afrag(w_hh, w_out, 24, 2, m, quad);
    }
    f32x4 zero4 = {0.f, 0.f, 0.f, 0.f};
    asm volatile("" : "+v"(af00), "+v"(af01), "+v"(af02), "+v"(af10),
                      "+v"(af11), "+v"(af12), "+v"(af20));
    asm volatile("" : "+v"(af21), "+v"(af22), "+v"(af30), "+v"(af31),
                      "+v"(af32), "+v"(af40), "+v"(af41));
    asm volatile("" : "+v"(af42), "+v"(af50), "+v"(af51), "+v"(af52),
                      "+v"(afy0), "+v"(afy1), "+v"(afy2), "+v"(zero4));

    // ---- per-lane cell params (exp2-domain prescaled); weights are shared
    // across batches, so the cell index alone determines them.
    const int sel  = (cc >= 6) ? (cc - 6) : cc;
    const int cell = 24 * wv + 4 * sel + quad;
    const float bias_i = LOG2E * (b_ih[0 * H_DIM + cell] + b_hh[0 * H_DIM + cell]);
    const float bias_f = LOG2E * (b_ih[1 * H_DIM + cell] + b_hh[1 * H_DIM + cell]);
    const float bias_g = 2.0f * LOG2E * (b_ih[2 * H_DIM + cell] + b_hh[2 * H_DIM + cell]);
    const float bias_o = LOG2E * (b_ih[3 * H_DIM + cell] + b_hh[3 * H_DIM + cell]);
    const float wih_i  = LOG2E * w_ih[0 * H_DIM + cell];
    const float wih_f  = LOG2E * w_ih[1 * H_DIM + cell];
    const float wih_g  = 2.0f * LOG2E * w_ih[2 * H_DIM + cell];
    const float wih_o  = LOG2E * w_ih[3 * H_DIM + cell];
    const float bout   = b_out[0];
    float c = 0.f;
    if (tid < 2 * H_DIM) (&h_s[0][0][0])[tid] = (_Float16)0.0f;  // buf 0
    __syncthreads();

    float x_cur_next = x_s[bsub][0];  // register prefetch of x[it] (own batch)

    // iter it: reads h_{it-1} (h_s[it&1]); makes h_it; y tile -> y_{it-1}
    for (int it = 0; it <= T_LEN + 1; ++it) {
        const int p = it & 1;

        f32x4 acc0, acc1, acc2, acc3, acc4, acc5, accy;
        const float x_cur = x_cur_next;

        if (it <= T_LEN) {
            // B-frag: col m -> batch bsub's h; lane reads its batch's K-chunk
            const f32x4 b0 = *reinterpret_cast<const f32x4*>(&h_s[p][bsub][quad * 8]);
            const f32x4 b1 = *reinterpret_cast<const f32x4*>(&h_s[p][bsub][32 + quad * 8]);
            const f32x4 b2 = *reinterpret_cast<const f32x4*>(&h_s[p][bsub][64 + quad * 8]);
            // x prefetch for it+1 (one lgkm group with the B-frag reads)
            x_cur_next = x_s[bsub][(it + 1 < T_LEN) ? (it + 1) : (T_LEN - 1)];

            acc0 = MFMA16(af00, b0, zero4);
            acc1 = MFMA16(af10, b0, zero4);
            acc2 = MFMA16(af20, b0, zero4);
            acc3 = MFMA16(af30, b0, zero4);
            acc4 = MFMA16(af40, b0, zero4);
            acc5 = MFMA16(af50, b0, zero4);
            acc0 = MFMA16(af01, b1, acc0);
            acc1 = MFMA16(af11, b1, acc1);
            acc2 = MFMA16(af21, b1, acc2);
            acc3 = MFMA16(af31, b1, acc3);
            acc4 = MFMA16(af41, b1, acc4);
            acc5 = MFMA16(af51, b1, acc5);
            acc0 = MFMA16(af02, b2, acc0);
            acc1 = MFMA16(af12, b2, acc1);
            acc2 = MFMA16(af22, b2, acc2);
            acc3 = MFMA16(af32, b2, acc3);
            acc4 = MFMA16(af42, b2, acc4);
            acc5 = MFMA16(af52, b2, acc5);
            if (wv == 3) {
                accy = MFMA16(afy0, b0, zero4);
                accy = MFMA16(afy1, b1, accy);
                accy = MFMA16(afy2, b2, accy);
                // row 0 (quad 0, reg 0), cols 0 and 8 = the two batches' y
                if (quad == 0 && cc == 0 && it > 0)
                    y_buf[bsub][((it - 1) >> 7) & 1][(it - 1) & (CHUNK - 1)] =
                        accy.x + bout;
            }
        }

        // ring flush: chunk [it-1-CHUNK, it-1) complete; wv0 -> batch 0,
        // wv1 -> batch 1, lanes 0..31 each store one f32x4
        if ((it & (CHUNK - 1)) == 1 && it > 1 && wv < 2 && lane < 32) {
            const int base = it - 1 - CHUNK;
            const int pb = (base >> 7) & 1;
            const f32x4 v =
                *reinterpret_cast<const f32x4*>(&y_buf[wv][pb][lane * 4]);
            float* yrow = y + (size_t)(2 * blockIdx.x + wv) * T_LEN;
            *reinterpret_cast<f32x4*>(&yrow[base + lane * 4]) = v;
        }

        if (it < T_LEN) {
            f32x4 g4 = acc0;
            if (sel == 1) g4 = acc1;
            if (sel == 2) g4 = acc2;
            if (sel == 3) g4 = acc3;
            if (sel == 4) g4 = acc4;
            if (sel == 5) g4 = acc5;
            const float s0 = g4.x + fmaf(x_cur, wih_i, bias_i);
            const float s1 = g4.y + fmaf(x_cur, wih_f, bias_f);
            const float s2 = g4.z + fmaf(x_cur, wih_g, bias_g);
            const float s3 = g4.w + fmaf(x_cur, wih_o, bias_o);
            const float ig = sig2(s0);
            const float fg = sig2(s1);
            const float gg = tanh2(s2);
            const float og = sig2(s3);
            c = fmaf(fg, c, ig * gg);
            const float h = og * tanh2(2.0f * LOG2E * c);
            if (cc < 6) h_s[p ^ 1][bsub][cell] = (_Float16)h;
        }
        __syncthreads();  // h_s[p^1] + y_buf ready (4-wave barrier)
    }
}

extern "C" void kernel_launch(void* const* d_in, const int* in_sizes, int n_in,
                              void* d_out, int out_size, void* d_ws, size_t ws_size,
                              hipStream_t stream) {
    const float* x     = (const float*)d_in[0];
    const float* w_ih  = (const float*)d_in[1];
    const float* w_hh  = (const float*)d_in[2];
    const float* b_ih  = (const float*)d_in[3];
    const float* b_hh  = (const float*)d_in[4];
    const float* w_out = (const float*)d_in[5];
    const float* b_out = (const float*)d_in[6];
    float* y = (float*)d_out;

    const int NBLK = 64;  // 2 batches per block (packed into B columns)
    lstm_mfma14_kernel<<<dim3(NBLK), dim3(NTHR), 0, stream>>>(
        x, w_ih, w_hh, b_ih, b_hh, w_out, b_out, y);
}

// Round 2
// 3058.951 us; speedup vs baseline: 1.4856x; 1.1384x over previous
//
#include <hip/hip_runtime.h>

// SimpleLSTM B=128,T=8192,H=96. R15: dedicated y-wave. R14 (2 batches packed
// into B columns, 4 waves, 1 wave/SIMD) won 23%; counters show ~75% of the
// 425 ns step is still serial chain (barrier + LDS burst + MFMA dep chain +
// activation). Remaining asymmetry: wave 3 carried the y tile (3 extra MFMAs
// + accy chain + y_buf store) and wv0/1 carried the ring flush -- the barrier
// waits for the slowest wave, so that's pure critical-path time. R15 moves y
// AND the ring flush to a 5th wave (320 thr) whose chain (read -> 3 MFMA ->
// scalar store) is far shorter than a gate chain; all 4 gate waves are now
// symmetric 18-MFMA chains with no flush branches. Also pads x_s rows so the
// two batches' x-prefetch reads land on different banks. Everything else
// (permuted W rows, exp2-domain prescale, named scalars, pinned A-frags,
// x register prefetch, y ring flush by 128) carried from R14.

#define T_LEN 8192
#define H_DIM 96
#define NTHR  320   // 5 waves: 4 gate waves + 1 y/flush wave
#define CHUNK 128
#define LOG2E 1.44269504f

typedef float    f32x4 __attribute__((ext_vector_type(4)));
typedef _Float16 half8 __attribute__((ext_vector_type(8)));

#define MFMA16(A, B, C)                                                        \
    __builtin_amdgcn_mfma_f32_16x16x32_f16(__builtin_bit_cast(half8, (A)),     \
                                           __builtin_bit_cast(half8, (B)),     \
                                           (C), 0, 0, 0)

__device__ __forceinline__ float sig2(float s) {   // sigmoid, s = log2e*pre
    return __builtin_amdgcn_rcpf(1.0f + __builtin_amdgcn_exp2f(-s));
}
__device__ __forceinline__ float tanh2(float sg) { // tanh, sg = 2log2e*pre
    return 1.0f - 2.0f * __builtin_amdgcn_rcpf(1.0f + __builtin_amdgcn_exp2f(sg));
}

__device__ __forceinline__ f32x4 load_afrag(const float* __restrict__ w_hh,
                                            const float* __restrict__ w_out,
                                            int mt, int kt, int m, int quad) {
    half8 f;
    if (mt < 24) {
        const int r = m & 3;                       // gate: 0=i 1=f 2=g 3=o
        const float scale = (r == 2) ? 2.0f * LOG2E : LOG2E;
        const int orig = r * 96 + 4 * mt + (m >> 2);
        const float* src = w_hh + orig * H_DIM + kt * 32 + quad * 8;
        #pragma unroll
        for (int jj = 0; jj < 8; ++jj) f[jj] = (_Float16)(scale * src[jj]);
    } else {  // y tile: row 0 = w_out (unscaled), rows 1..15 = 0
        #pragma unroll
        for (int jj = 0; jj < 8; ++jj)
            f[jj] = (m == 0) ? (_Float16)w_out[kt * 32 + quad * 8 + jj]
                             : (_Float16)0.0f;
    }
    return __builtin_bit_cast(f32x4, f);
}

__global__ __launch_bounds__(NTHR, 2) void lstm_mfma15_kernel(
    const float* __restrict__ x,      // [B, T]
    const float* __restrict__ w_ih,   // [4H]
    const float* __restrict__ w_hh,   // [4H, H]
    const float* __restrict__ b_ih,   // [4H]
    const float* __restrict__ b_hh,   // [4H]
    const float* __restrict__ w_out,  // [H]
    const float* __restrict__ b_out,  // [1]
    float* __restrict__ y)            // [B, T]
{
    const int tid  = threadIdx.x;
    const int wv   = tid >> 6;        // wave 0..3 = gates, 4 = y/flush
    const int lane = tid & 63;
    const int m    = lane & 15;       // A-row / D-column index
    const int quad = lane >> 4;       // D row group / B K-chunk
    const int cc   = m & 7;           // within-batch column
    const int bsub = m >> 3;          // 0: batch 2b, 1: batch 2b+1

    __shared__ __align__(16) _Float16 h_s[2][2][H_DIM];       // [buf][bsub][cell]
    __shared__ __align__(16) float    y_buf[2][2][CHUNK];     // [bsub][ring][i]
    __shared__ __align__(16) float    x_s[2][T_LEN + 8];      // +8 pad: bank-split

    // ---- stage both batches' x into LDS (rows 2b, 2b+1 are contiguous)
    {
        const float* xpair = x + (size_t)(2 * blockIdx.x) * T_LEN;
        for (int i = tid * 4; i < T_LEN; i += NTHR * 4) {
            *reinterpret_cast<f32x4*>(&x_s[0][i]) =
                *reinterpret_cast<const f32x4*>(&xpair[i]);
            *reinterpret_cast<f32x4*>(&x_s[1][i]) =
                *reinterpret_cast<const f32x4*>(&xpair[T_LEN + i]);
        }
    }

    // ---- A fragments (named, pinned). Gate wave wv owns tiles 6wv..6wv+5;
    // y-wave (wv==4): mt0=24 -> load_afrag's y path for all (only afy used).
    const int mt0 = 6 * wv;
    f32x4 af00 = load_afrag(w_hh, w_out, mt0 + 0, 0, m, quad);
    f32x4 af01 = load_afrag(w_hh, w_out, mt0 + 0, 1, m, quad);
    f32x4 af02 = load_afrag(w_hh, w_out, mt0 + 0, 2, m, quad);
    f32x4 af10 = load_afrag(w_hh, w_out, mt0 + 1, 0, m, quad);
    f32x4 af11 = load_afrag(w_hh, w_out, mt0 + 1, 1, m, quad);
    f32x4 af12 = load_afrag(w_hh, w_out, mt0 + 1, 2, m, quad);
    f32x4 af20 = load_afrag(w_hh, w_out, mt0 + 2, 0, m, quad);
    f32x4 af21 = load_afrag(w_hh, w_out, mt0 + 2, 1, m, quad);
    f32x4 af22 = load_afrag(w_hh, w_out, mt0 + 2, 2, m, quad);
    f32x4 af30 = load_afrag(w_hh, w_out, mt0 + 3, 0, m, quad);
    f32x4 af31 = load_afrag(w_hh, w_out, mt0 + 3, 1, m, quad);
    f32x4 af32 = load_afrag(w_hh, w_out, mt0 + 3, 2, m, quad);
    f32x4 af40 = load_afrag(w_hh, w_out, mt0 + 4, 0, m, quad);
    f32x4 af41 = load_afrag(w_hh, w_out, mt0 + 4, 1, m, quad);
    f32x4 af42 = load_afrag(w_hh, w_out, mt0 + 4, 2, m, quad);
    f32x4 af50 = load_afrag(w_hh, w_out, mt0 + 5, 0, m, quad);
    f32x4 af51 = load_afrag(w_hh, w_out, mt0 + 5, 1, m, quad);
    f32x4 af52 = load_afrag(w_hh, w_out, mt0 + 5, 2, m, quad);
    f32x4 afy0 = {0.f, 0.f, 0.f, 0.f};
    f32x4 afy1 = {0.f, 0.f, 0.f, 0.f};
    f32x4 afy2 = {0.f, 0.f, 0.f, 0.f};
    if (wv == 4) {
        afy0 = load_afrag(w_hh, w_out, 24, 0, m, quad);
        afy1 = load_afrag(w_hh, w_out, 24, 1, m, quad);
        afy2 = load_afrag(w_hh, w_out, 24, 2, m, quad);
    }
    f32x4 zero4 = {0.f, 0.f, 0.f, 0.f};
    asm volatile("" : "+v"(af00), "+v"(af01), "+v"(af02), "+v"(af10),
                      "+v"(af11), "+v"(af12), "+v"(af20));
    asm volatile("" : "+v"(af21), "+v"(af22), "+v"(af30), "+v"(af31),
                      "+v"(af32), "+v"(af40), "+v"(af41));
    asm volatile("" : "+v"(af42), "+v"(af50), "+v"(af51), "+v"(af52),
                      "+v"(afy0), "+v"(afy1), "+v"(afy2), "+v"(zero4));

    // ---- per-lane cell params (gate waves only; exp2-domain prescaled)
    const int sel  = (cc >= 6) ? (cc - 6) : cc;
    const int cell = (wv < 4) ? (24 * wv + 4 * sel + quad) : 0;  // clamp: no OOB
    const float bias_i = LOG2E * (b_ih[0 * H_DIM + cell] + b_hh[0 * H_DIM + cell]);
    const float bias_f = LOG2E * (b_ih[1 * H_DIM + cell] + b_hh[1 * H_DIM + cell]);
    const float bias_g = 2.0f * LOG2E * (b_ih[2 * H_DIM + cell] + b_hh[2 * H_DIM + cell]);
    const float bias_o = LOG2E * (b_ih[3 * H_DIM + cell] + b_hh[3 * H_DIM + cell]);
    const float wih_i  = LOG2E * w_ih[0 * H_DIM + cell];
    const float wih_f  = LOG2E * w_ih[1 * H_DIM + cell];
    const float wih_g  = 2.0f * LOG2E * w_ih[2 * H_DIM + cell];
    const float wih_o  = LOG2E * w_ih[3 * H_DIM + cell];
    const float bout   = b_out[0];
    float c = 0.f;
    if (tid < 2 * H_DIM) (&h_s[0][0][0])[tid] = (_Float16)0.0f;  // buf 0
    __syncthreads();

    float x_cur_next = x_s[bsub][0];  // register prefetch of x[it] (own batch)

    // iter it: gate waves read h_{it-1} (h_s[it&1]) and produce h_it
    // (h_s[it&1 ^1]); y-wave reads the same buffer and stores y_{it-1}.
    for (int it = 0; it <= T_LEN + 1; ++it) {
        const int p = it & 1;

        if (wv < 4) {
            // ------------- gate wave -------------
            if (it < T_LEN) {
                const f32x4 b0 = *reinterpret_cast<const f32x4*>(&h_s[p][bsub][quad * 8]);
                const f32x4 b1 = *reinterpret_cast<const f32x4*>(&h_s[p][bsub][32 + quad * 8]);
                const f32x4 b2 = *reinterpret_cast<const f32x4*>(&h_s[p][bsub][64 + quad * 8]);
                const float x_cur = x_cur_next;
                // x prefetch for it+1 (same lgkm group as B-frag reads)
                x_cur_next = x_s[bsub][(it + 1 < T_LEN) ? (it + 1) : (T_LEN - 1)];

                f32x4 acc0 = MFMA16(af00, b0, zero4);
                f32x4 acc1 = MFMA16(af10, b0, zero4);
                f32x4 acc2 = MFMA16(af20, b0, zero4);
                f32x4 acc3 = MFMA16(af30, b0, zero4);
                f32x4 acc4 = MFMA16(af40, b0, zero4);
                f32x4 acc5 = MFMA16(af50, b0, zero4);
                acc0 = MFMA16(af01, b1, acc0);
                acc1 = MFMA16(af11, b1, acc1);
                acc2 = MFMA16(af21, b1, acc2);
                acc3 = MFMA16(af31, b1, acc3);
                acc4 = MFMA16(af41, b1, acc4);
                acc5 = MFMA16(af51, b1, acc5);
                acc0 = MFMA16(af02, b2, acc0);
                acc1 = MFMA16(af12, b2, acc1);
                acc2 = MFMA16(af22, b2, acc2);
                acc3 = MFMA16(af32, b2, acc3);
                acc4 = MFMA16(af42, b2, acc4);
                acc5 = MFMA16(af52, b2, acc5);

                f32x4 g4 = acc0;
                if (sel == 1) g4 = acc1;
                if (sel == 2) g4 = acc2;
                if (sel == 3) g4 = acc3;
                if (sel == 4) g4 = acc4;
                if (sel == 5) g4 = acc5;
                const float s0 = g4.x + fmaf(x_cur, wih_i, bias_i);
                const float s1 = g4.y + fmaf(x_cur, wih_f, bias_f);
                const float s2 = g4.z + fmaf(x_cur, wih_g, bias_g);
                const float s3 = g4.w + fmaf(x_cur, wih_o, bias_o);
                const float ig = sig2(s0);
                const float fg = sig2(s1);
                const float gg = tanh2(s2);
                const float og = sig2(s3);
                c = fmaf(fg, c, ig * gg);
                const float h = og * tanh2(2.0f * LOG2E * c);
                if (cc < 6) h_s[p ^ 1][bsub][cell] = (_Float16)h;
            }
        } else {
            // ------------- y / flush wave -------------
            if (it <= T_LEN) {
                const f32x4 b0 = *reinterpret_cast<const f32x4*>(&h_s[p][bsub][quad * 8]);
                const f32x4 b1 = *reinterpret_cast<const f32x4*>(&h_s[p][bsub][32 + quad * 8]);
                const f32x4 b2 = *reinterpret_cast<const f32x4*>(&h_s[p][bsub][64 + quad * 8]);
                f32x4 accy = MFMA16(afy0, b0, zero4);
                accy = MFMA16(afy1, b1, accy);
                accy = MFMA16(afy2, b2, accy);
                // D row 0 (quad 0, reg 0); cols 0 and 8 = the two batches' y
                if (quad == 0 && cc == 0 && it > 0)
                    y_buf[bsub][((it - 1) >> 7) & 1][(it - 1) & (CHUNK - 1)] =
                        accy.x + bout;
            }
            // ring flush: chunk [it-1-CHUNK, it-1) complete; lanes 0..31 ->
            // batch 0, lanes 32..63 -> batch 1 (one f32x4 each)
            if ((it & (CHUNK - 1)) == 1 && it > 1) {
                const int base = it - 1 - CHUNK;
                const int pb   = (base >> 7) & 1;
                const int bsel = lane >> 5;
                const int li   = lane & 31;
                const f32x4 v =
                    *reinterpret_cast<const f32x4*>(&y_buf[bsel][pb][li * 4]);
                float* yrow = y + (size_t)(2 * blockIdx.x + bsel) * T_LEN;
                *reinterpret_cast<f32x4*>(&yrow[base + li * 4]) = v;
            }
        }
        __syncthreads();  // h_s[p^1] + y_buf ready (5-wave barrier)
    }
}

extern "C" void kernel_launch(void* const* d_in, const int* in_sizes, int n_in,
                              void* d_out, int out_size, void* d_ws, size_t ws_size,
                              hipStream_t stream) {
    const float* x     = (const float*)d_in[0];
    const float* w_ih  = (const float*)d_in[1];
    const float* w_hh  = (const float*)d_in[2];
    const float* b_ih  = (const float*)d_in[3];
    const float* b_hh  = (const float*)d_in[4];
    const float* w_out = (const float*)d_in[5];
    const float* b_out = (const float*)d_in[6];
    float* y = (float*)d_out;

    const int NBLK = 64;  // 2 batches per block (packed into B columns)
    lstm_mfma15_kernel<<<dim3(NBLK), dim3(NTHR), 0, stream>>>(
        x, w_ih, w_hh, b_ih, b_hh, w_out, b_out, y);
}